// Round 8
// baseline (84.368 us; speedup 1.0000x reference)
//
#include <hip/hip_runtime.h>
#include <math.h>

#define BB 4
#define NN 4096
#define DD 128
#define MM (BB*NN)   // 16384

typedef __attribute__((ext_vector_type(8))) short short8;
typedef __attribute__((ext_vector_type(4))) float f32x4;

__device__ inline short f2bf(float f) {
    unsigned u = __float_as_uint(f);
    u = (u + 0x7FFFu + ((u >> 16) & 1u)) >> 16;
    return (short)u;
}
__device__ inline float bf2f(short s) {
    return __uint_as_float(((unsigned)(unsigned short)s) << 16);
}
__device__ inline short8 pack_bf8(float4 a, float4 b) {
    short8 o;
    o[0] = f2bf(a.x); o[1] = f2bf(a.y); o[2] = f2bf(a.z); o[3] = f2bf(a.w);
    o[4] = f2bf(b.x); o[5] = f2bf(b.y); o[6] = f2bf(b.z); o[7] = f2bf(b.w);
    return o;
}
// swizzled LDS byte offset for a [32][128] bf16 tile (2-way max on b128 reads)
__device__ inline int swzoff(int row, int col) {
    return ((row * 128 + col) * 2) ^ ((row & 7) << 4);
}

// ---------------------------------------------------------------- weight preconvert to bf16 frag layout
// frag slot j = nt*256 + ks*64 + l ; elem i (0..7) = W[nt*16 + (l&15)][32*ks + 8*(l>>4) + i]
__global__ __launch_bounds__(256) void wprep(const float* __restrict__ w0, const float* __restrict__ w1,
                                             const float* __restrict__ w2, const float* __restrict__ w3,
                                             const float* __restrict__ w4, short* __restrict__ wf) {
    int m = blockIdx.x >> 3;
    int j = (blockIdx.x & 7) * 256 + threadIdx.x;
    const float* W = (m == 0) ? w0 : (m == 1) ? w1 : (m == 2) ? w2 : (m == 3) ? w3 : w4;
    int nt = j >> 8, ks = (j >> 6) & 3, l = j & 63, r = l & 15, g = l >> 4;
    const float* src = W + (size_t)(nt * 16 + r) * DD + 32 * ks + 8 * g;
    float4 a = *(const float4*)src;
    float4 b = *(const float4*)(src + 4);
    ((short8*)(wf + (size_t)m * 16384))[j] = pack_bf8(a, b);
}

// ---------------------------------------------------------------- LN1 + K,V GEMMs + ctx partial (atomic-free)
__global__ __launch_bounds__(256) void lnctx(const float* __restrict__ x,
                                             const float* __restrict__ lng,
                                             const float* __restrict__ lnb,
                                             const short* __restrict__ wf,   // wk frags, wv at +16384
                                             float* __restrict__ partC,
                                             float* __restrict__ pcs) {
    __shared__ float ekL[32][132];
    __shared__ float vL[32][132];
    int t = threadIdx.x;
    int block_row = blockIdx.x * 32;
    int w = t >> 6, l = t & 63, r = l & 15, g = l >> 4;
    int rh = w >> 1, nt0 = (w & 1) << 2;
    int row0 = block_row + rh * 16;

    const float* ap = x + (size_t)(row0 + r) * DD + 8 * g;
    float4 av0[4], av1[4];
    #pragma unroll
    for (int ks = 0; ks < 4; ks++) {
        av0[ks] = *(const float4*)(ap + 32 * ks);
        av1[ks] = *(const float4*)(ap + 32 * ks + 4);
    }
    float s = 0.f, ss = 0.f;
    #pragma unroll
    for (int ks = 0; ks < 4; ks++) {
        float4 a = av0[ks], b = av1[ks];
        s  += a.x + a.y + a.z + a.w + b.x + b.y + b.z + b.w;
        ss += a.x*a.x + a.y*a.y + a.z*a.z + a.w*a.w + b.x*b.x + b.y*b.y + b.z*b.z + b.w*b.w;
    }
    s  += __shfl_xor(s, 16);  s  += __shfl_xor(s, 32);
    ss += __shfl_xor(ss, 16); ss += __shfl_xor(ss, 32);
    float mu = s * (1.0f / DD);
    float var = ss * (1.0f / DD) - mu * mu;
    float rs = rsqrtf(var + 1e-6f);

    short8 af[4];
    #pragma unroll
    for (int ks = 0; ks < 4; ks++) {
        float4 g0 = *(const float4*)(lng + 32 * ks + 8 * g);
        float4 g1 = *(const float4*)(lng + 32 * ks + 8 * g + 4);
        float4 b0 = *(const float4*)(lnb + 32 * ks + 8 * g);
        float4 b1 = *(const float4*)(lnb + 32 * ks + 8 * g + 4);
        float4 n0, n1;
        n0.x = (av0[ks].x - mu) * rs * g0.x + b0.x;
        n0.y = (av0[ks].y - mu) * rs * g0.y + b0.y;
        n0.z = (av0[ks].z - mu) * rs * g0.z + b0.z;
        n0.w = (av0[ks].w - mu) * rs * g0.w + b0.w;
        n1.x = (av1[ks].x - mu) * rs * g1.x + b1.x;
        n1.y = (av1[ks].y - mu) * rs * g1.y + b1.y;
        n1.z = (av1[ks].z - mu) * rs * g1.z + b1.z;
        n1.w = (av1[ks].w - mu) * rs * g1.w + b1.w;
        af[ks] = pack_bf8(n0, n1);
    }

    f32x4 acc[2][4];
    #pragma unroll
    for (int m = 0; m < 2; m++)
        #pragma unroll
        for (int n = 0; n < 4; n++) acc[m][n] = (f32x4){0.f, 0.f, 0.f, 0.f};
    const short8* wp8 = (const short8*)wf;
    #pragma unroll
    for (int ks = 0; ks < 4; ks++)
        #pragma unroll
        for (int m = 0; m < 2; m++)
            #pragma unroll
            for (int n = 0; n < 4; n++)
                acc[m][n] = __builtin_amdgcn_mfma_f32_16x16x32_bf16(
                    af[ks], wp8[(size_t)m * 2048 + ((nt0 + n) * 4 + ks) * 64 + l], acc[m][n], 0, 0, 0);

    #pragma unroll
    for (int n = 0; n < 4; n++) {
        int col = (nt0 + n) * 16 + r;
        #pragma unroll
        for (int j = 0; j < 4; j++) {
            int rowL = rh * 16 + 4 * g + j;
            ekL[rowL][col] = __expf(acc[0][n][j]);
            vL[rowL][col]  = acc[1][n][j];
        }
    }
    __syncthreads();

    int h = t >> 5, sub = t & 31, d = sub >> 1, e0 = (sub & 1) * 8;
    float cs = 0.f;
    float sc[8] = {0.f, 0.f, 0.f, 0.f, 0.f, 0.f, 0.f, 0.f};
    #pragma unroll 8
    for (int row = 0; row < 32; row++) {
        float ekv = ekL[row][h * 16 + d];
        float4 v0 = *(const float4*)&vL[row][h * 16 + e0];
        float4 v1 = *(const float4*)&vL[row][h * 16 + e0 + 4];
        sc[0] += ekv * v0.x; sc[1] += ekv * v0.y; sc[2] += ekv * v0.z; sc[3] += ekv * v0.w;
        sc[4] += ekv * v1.x; sc[5] += ekv * v1.y; sc[6] += ekv * v1.z; sc[7] += ekv * v1.w;
        cs += ekv;
    }
    float* cb = partC + (size_t)blockIdx.x * 2048 + h * 256 + d * 16 + e0;
    *(float4*)cb       = (float4){sc[0], sc[1], sc[2], sc[3]};
    *(float4*)(cb + 4) = (float4){sc[4], sc[5], sc[6], sc[7]};
    if ((sub & 1) == 0) pcs[(size_t)blockIdx.x * 128 + h * 16 + d] = cs;
}

// ---------------------------------------------------------------- ctx reduce (merged) + fold wo -> mt frag
// grid 32 = (b, nt). Each block reduces the 128 chunk-partials of its batch itself.
__global__ __launch_bounds__(256) void build_mt_k(const float* __restrict__ partC,
                                                  const float* __restrict__ pcs,
                                                  const float* __restrict__ wo,
                                                  short* __restrict__ mtfrag) {
    int b = blockIdx.x >> 3, nt = blockIdx.x & 7;
    int t = threadIdx.x;
    __shared__ float ctxL[2048];
    __shared__ float csL[128];
    __shared__ float woL[2048];
    {
        float s[8] = {0.f,0.f,0.f,0.f,0.f,0.f,0.f,0.f};
        for (int c = 0; c < 128; c++) {
            const float* pp = partC + (size_t)(b * 128 + c) * 2048 + t;
            #pragma unroll
            for (int i = 0; i < 8; i++) s[i] += pp[i * 256];
        }
        #pragma unroll
        for (int i = 0; i < 8; i++) ctxL[i * 256 + t] = s[i];
    }
    #pragma unroll
    for (int i = 0; i < 8; i++) {
        int idx = i * 256 + t;
        woL[idx] = wo[(size_t)(nt * 16) * DD + idx];
    }
    if (t < 128) {
        float s = 0.f;
        #pragma unroll 8
        for (int c = 0; c < 128; c++) s += pcs[(size_t)(b * 128 + c) * 128 + t];
        csL[t] = s;
    }
    __syncthreads();
    int ks = (t >> 6) & 3, l = t & 63, r = l & 15, g = l >> 4;
    short8 o;
    #pragma unroll
    for (int i2 = 0; i2 < 8; i2++) {
        int k = 32 * ks + 8 * g + i2;
        float inv = 1.0f / csL[k];
        const float* wrow = woL + r * DD + (k >> 4) * 16;
        float s = 0.f;
        #pragma unroll
        for (int eo = 0; eo < 16; eo++) s += ctxL[k * 16 + eo] * wrow[eo];
        o[i2] = f2bf(s * inv);
    }
    ((short8*)(mtfrag + (size_t)b * 16384))[nt * 256 + t] = o;
}

// ---------------------------------------------------------------- fused mid:
// LN1 -> q (MFMA + feature softmax) -> xmid = q@Mt + bo + x -> LN2 -> gelu GEMM -> final GEMM
__global__ __launch_bounds__(256) void fused_mid(const float* __restrict__ x,
                                                 const float* __restrict__ ln1g,
                                                 const float* __restrict__ ln1b,
                                                 const short* __restrict__ wqf,
                                                 const short* __restrict__ mtf,
                                                 const float* __restrict__ bo,
                                                 const float* __restrict__ ln2g,
                                                 const float* __restrict__ ln2b,
                                                 const short* __restrict__ w1f,
                                                 const float* __restrict__ b1,
                                                 const short* __restrict__ w2f,
                                                 const float* __restrict__ b2,
                                                 float* __restrict__ xfinal,
                                                 short* __restrict__ xbf) {
    __shared__ __align__(16) char ex[32 * 128 * 2];   // bf16 swizzled exchange (q, y, h1)
    __shared__ float ex2f[32][132];                   // f32 x tile for residual
    __shared__ float redS[4][16], redSS[4][16];
    int t = threadIdx.x;
    int block_row = blockIdx.x * 32;
    int w = t >> 6, l = t & 63, r = l & 15, g = l >> 4;
    int rh = w >> 1, nt0 = (w & 1) << 2;
    int row0 = block_row + rh * 16;
    int rrow = rh * 16 + r;

    const float* ap = x + (size_t)(row0 + r) * DD + 8 * g;
    float4 av0[4], av1[4];
    #pragma unroll
    for (int ks = 0; ks < 4; ks++) {
        av0[ks] = *(const float4*)(ap + 32 * ks);
        av1[ks] = *(const float4*)(ap + 32 * ks + 4);
    }
    if ((w & 1) == 0) {
        #pragma unroll
        for (int ks = 0; ks < 4; ks++) {
            *(float4*)&ex2f[rrow][32 * ks + 8 * g]     = av0[ks];
            *(float4*)&ex2f[rrow][32 * ks + 8 * g + 4] = av1[ks];
        }
    }
    float s = 0.f, ss = 0.f;
    #pragma unroll
    for (int ks = 0; ks < 4; ks++) {
        float4 a = av0[ks], b = av1[ks];
        s  += a.x + a.y + a.z + a.w + b.x + b.y + b.z + b.w;
        ss += a.x*a.x + a.y*a.y + a.z*a.z + a.w*a.w + b.x*b.x + b.y*b.y + b.z*b.z + b.w*b.w;
    }
    s  += __shfl_xor(s, 16);  s  += __shfl_xor(s, 32);
    ss += __shfl_xor(ss, 16); ss += __shfl_xor(ss, 32);
    float mu1 = s * (1.0f / DD);
    float var1 = ss * (1.0f / DD) - mu1 * mu1;
    float rs1 = rsqrtf(var1 + 1e-6f);
    short8 af[4];
    #pragma unroll
    for (int ks = 0; ks < 4; ks++) {
        float4 g0 = *(const float4*)(ln1g + 32 * ks + 8 * g);
        float4 g1 = *(const float4*)(ln1g + 32 * ks + 8 * g + 4);
        float4 b0 = *(const float4*)(ln1b + 32 * ks + 8 * g);
        float4 b1v = *(const float4*)(ln1b + 32 * ks + 8 * g + 4);
        float4 n0, n1;
        n0.x = (av0[ks].x - mu1) * rs1 * g0.x + b0.x;
        n0.y = (av0[ks].y - mu1) * rs1 * g0.y + b0.y;
        n0.z = (av0[ks].z - mu1) * rs1 * g0.z + b0.z;
        n0.w = (av0[ks].w - mu1) * rs1 * g0.w + b0.w;
        n1.x = (av1[ks].x - mu1) * rs1 * g1.x + b1v.x;
        n1.y = (av1[ks].y - mu1) * rs1 * g1.y + b1v.y;
        n1.z = (av1[ks].z - mu1) * rs1 * g1.z + b1v.z;
        n1.w = (av1[ks].w - mu1) * rs1 * g1.w + b1v.w;
        af[ks] = pack_bf8(n0, n1);
    }

    const short8* qp = (const short8*)wqf;
    f32x4 accq[4];
    #pragma unroll
    for (int n = 0; n < 4; n++) accq[n] = (f32x4){0.f, 0.f, 0.f, 0.f};
    #pragma unroll
    for (int ks = 0; ks < 4; ks++)
        #pragma unroll
        for (int n = 0; n < 4; n++)
            accq[n] = __builtin_amdgcn_mfma_f32_16x16x32_bf16(
                af[ks], qp[((nt0 + n) * 4 + ks) * 64 + l], accq[n], 0, 0, 0);
    #pragma unroll
    for (int n = 0; n < 4; n++) {
        int col = (nt0 + n) * 16 + r;
        #pragma unroll
        for (int j = 0; j < 4; j++) {
            float e = __expf(accq[n][j]);
            float sm = e;
            sm += __shfl_xor(sm, 1); sm += __shfl_xor(sm, 2);
            sm += __shfl_xor(sm, 4); sm += __shfl_xor(sm, 8);
            *(short*)(ex + swzoff(rh * 16 + 4 * g + j, col)) = f2bf(e / sm);
        }
    }
    __syncthreads();

    short8 qf[4];
    #pragma unroll
    for (int ks = 0; ks < 4; ks++)
        qf[ks] = *(const short8*)(ex + swzoff(rrow, 32 * ks + 8 * g));
    float xres[4][4];
    #pragma unroll
    for (int n = 0; n < 4; n++)
        #pragma unroll
        for (int j = 0; j < 4; j++)
            xres[n][j] = ex2f[rh * 16 + 4 * g + j][(nt0 + n) * 16 + r];

    const short8* mp = (const short8*)(mtf + (size_t)(block_row >> 12) * 16384);
    f32x4 acc[4];
    #pragma unroll
    for (int n = 0; n < 4; n++) acc[n] = (f32x4){0.f, 0.f, 0.f, 0.f};
    #pragma unroll
    for (int ks = 0; ks < 4; ks++)
        #pragma unroll
        for (int n = 0; n < 4; n++)
            acc[n] = __builtin_amdgcn_mfma_f32_16x16x32_bf16(
                qf[ks], mp[((nt0 + n) * 4 + ks) * 64 + l], acc[n], 0, 0, 0);

    float vv[4][4];
    #pragma unroll
    for (int n = 0; n < 4; n++) {
        int col = (nt0 + n) * 16 + r;
        float bv = bo[col];
        #pragma unroll
        for (int j = 0; j < 4; j++)
            vv[n][j] = acc[n][j] + bv + xres[n][j];
    }

    #pragma unroll
    for (int j = 0; j < 4; j++) {
        float s1  = vv[0][j] + vv[1][j] + vv[2][j] + vv[3][j];
        float s2 = vv[0][j]*vv[0][j] + vv[1][j]*vv[1][j] + vv[2][j]*vv[2][j] + vv[3][j]*vv[3][j];
        s1 += __shfl_xor(s1, 1); s1 += __shfl_xor(s1, 2); s1 += __shfl_xor(s1, 4); s1 += __shfl_xor(s1, 8);
        s2 += __shfl_xor(s2, 1); s2 += __shfl_xor(s2, 2); s2 += __shfl_xor(s2, 4); s2 += __shfl_xor(s2, 8);
        if (r == 0) { redS[w][4 * g + j] = s1; redSS[w][4 * g + j] = s2; }
    }
    __syncthreads();
    int base = w & 2;
    #pragma unroll
    for (int j = 0; j < 4; j++) {
        int rr = 4 * g + j;
        float S  = redS[base][rr]  + redS[base + 1][rr];
        float SS = redSS[base][rr] + redSS[base + 1][rr];
        float mu = S * (1.0f / DD);
        float var = SS * (1.0f / DD) - mu * mu;
        float rs = rsqrtf(var + 1e-6f);
        int rowL = rh * 16 + rr;
        #pragma unroll
        for (int n = 0; n < 4; n++) {
            int col = (nt0 + n) * 16 + r;
            float y = (vv[n][j] - mu) * rs * ln2g[col] + ln2b[col];
            *(short*)(ex + swzoff(rowL, col)) = f2bf(y);
        }
    }
    __syncthreads();
    short8 yf[4];
    #pragma unroll
    for (int ks = 0; ks < 4; ks++)
        yf[ks] = *(const short8*)(ex + swzoff(rrow, 32 * ks + 8 * g));
    __syncthreads();
    const short8* w1p = (const short8*)w1f;
    f32x4 acc2[4];
    #pragma unroll
    for (int n = 0; n < 4; n++) acc2[n] = (f32x4){0.f, 0.f, 0.f, 0.f};
    #pragma unroll
    for (int ks = 0; ks < 4; ks++)
        #pragma unroll
        for (int n = 0; n < 4; n++)
            acc2[n] = __builtin_amdgcn_mfma_f32_16x16x32_bf16(
                yf[ks], w1p[((nt0 + n) * 4 + ks) * 64 + l], acc2[n], 0, 0, 0);
    #pragma unroll
    for (int n = 0; n < 4; n++) {
        int col = (nt0 + n) * 16 + r;
        float bv = b1[col];
        #pragma unroll
        for (int j = 0; j < 4; j++) {
            float v = acc2[n][j] + bv;
            v = 0.5f * v * (1.0f + erff(v * 0.70710678118654752f));
            *(short*)(ex + swzoff(rh * 16 + 4 * g + j, col)) = f2bf(v);
        }
    }
    __syncthreads();
    short8 hf[4];
    #pragma unroll
    for (int ks = 0; ks < 4; ks++)
        hf[ks] = *(const short8*)(ex + swzoff(rrow, 32 * ks + 8 * g));
    const short8* w2p = (const short8*)w2f;
    f32x4 acc3[4];
    #pragma unroll
    for (int n = 0; n < 4; n++) acc3[n] = (f32x4){0.f, 0.f, 0.f, 0.f};
    #pragma unroll
    for (int ks = 0; ks < 4; ks++)
        #pragma unroll
        for (int n = 0; n < 4; n++)
            acc3[n] = __builtin_amdgcn_mfma_f32_16x16x32_bf16(
                hf[ks], w2p[((nt0 + n) * 4 + ks) * 64 + l], acc3[n], 0, 0, 0);
    #pragma unroll
    for (int n = 0; n < 4; n++) {
        int col = (nt0 + n) * 16 + r;
        float bv = b2[col];
        #pragma unroll
        for (int j = 0; j < 4; j++) {
            float v = acc3[n][j] + bv + vv[n][j];
            size_t row = (size_t)(row0 + 4 * g + j);
            xfinal[row * DD + col] = v;
            xbf[row * DD + col] = f2bf(v);
        }
    }
}

// ---------------------------------------------------------------- S partials (512 threads, 8 waves/CU)
// part[blk][e*128 + d] = sum_{64 rows} x[row,d] * fx[row,e]
__global__ __launch_bounds__(512) void sbuild_p(const short* __restrict__ xf,
                                                const float* __restrict__ fx,
                                                short* __restrict__ part) {
    int b = blockIdx.x >> 6, chunk = blockIdx.x & 63;
    int t = threadIdx.x;
    __shared__ float xs[64 * 128], fs[64 * 128];
    const short* xb = xf + ((size_t)b * NN + chunk * 64) * DD;
    const float* fb = fx + ((size_t)b * NN + chunk * 64) * DD;
    const short8* xg = (const short8*)xb;
    float4* xs4 = (float4*)xs; float4* fs4 = (float4*)fs;
    const float4* fg = (const float4*)fb;
    #pragma unroll
    for (int i = 0; i < 2; i++) {
        int j = i * 512 + t;             // 1024 short8
        short8 s8 = xg[j];
        float4 a = {bf2f(s8[0]), bf2f(s8[1]), bf2f(s8[2]), bf2f(s8[3])};
        float4 c = {bf2f(s8[4]), bf2f(s8[5]), bf2f(s8[6]), bf2f(s8[7])};
        xs4[2 * j] = a; xs4[2 * j + 1] = c;
    }
    #pragma unroll
    for (int i = 0; i < 4; i++) {
        int j = i * 512 + t;             // 2048 float4
        fs4[j] = fg[j];
    }
    __syncthreads();
    int td = t & 15, te = t >> 4;        // d0 = td*8 (8 d), e0 = te*4 (4 e)
    float acc[8][4];
    #pragma unroll
    for (int a = 0; a < 8; a++)
        #pragma unroll
        for (int c = 0; c < 4; c++) acc[a][c] = 0.f;
    for (int r = 0; r < 64; r++) {
        float4 x0 = xs4[r * 32 + td * 2], x1 = xs4[r * 32 + td * 2 + 1];
        float4 f0 = fs4[r * 32 + te];
        float xv[8] = {x0.x, x0.y, x0.z, x0.w, x1.x, x1.y, x1.z, x1.w};
        float fv[4] = {f0.x, f0.y, f0.z, f0.w};
        #pragma unroll
        for (int a = 0; a < 8; a++)
            #pragma unroll
            for (int c = 0; c < 4; c++) acc[a][c] = fmaf(xv[a], fv[c], acc[a][c]);
    }
    short* pb = part + (size_t)blockIdx.x * 16384;
    #pragma unroll
    for (int ci = 0; ci < 4; ci++) {
        short8 o;
        #pragma unroll
        for (int a = 0; a < 8; a++) o[a] = f2bf(acc[a][ci]);
        *(short8*)(pb + (size_t)(te * 4 + ci) * 128 + td * 8) = o;
    }
}

// ---------------------------------------------------------------- reduce S partials -> plain S_T[b][e][d] f32
// grid 512 = (b, e): coalesced 256B reads across d
__global__ __launch_bounds__(256) void sreduce2(const short* __restrict__ part,
                                                float* __restrict__ S_T) {
    int b = blockIdx.x >> 7, e = blockIdx.x & 127;
    int t = threadIdx.x;
    int d = t & 127, half = t >> 7;
    float s = 0.f;
    #pragma unroll 4
    for (int ch = half * 32; ch < half * 32 + 32; ch++)
        s += bf2f(part[(size_t)(b * 64 + ch) * 16384 + e * 128 + d]);
    __shared__ float red[128];
    if (half) red[d] = s;
    __syncthreads();
    if (!half) S_T[((size_t)b * 128 + e) * 128 + d] = s + red[d];
}

// ---------------------------------------------------------------- final sigmoid GEMM (B-frags from plain S_T)
__global__ __launch_bounds__(256) void gemm_sig(const short* __restrict__ A,
                                                const float* __restrict__ S_T,
                                                float* __restrict__ Cf) {
    int t = threadIdx.x;
    int block_row = blockIdx.x * 32;
    int w = t >> 6, l = t & 63, r = l & 15, g = l >> 4;
    int row0 = block_row + ((w >> 1) << 4);
    int nt0 = (w & 1) << 2;
    const short8* ap = (const short8*)(A + (size_t)(row0 + r) * DD + 8 * g);
    short8 af[4];
    #pragma unroll
    for (int ks = 0; ks < 4; ks++) af[ks] = ap[ks * 4];
    // build B-frags: elem i = S[k=32ks+8g+i][e=nt*16+r] = S_T[e*128 + k]
    const float* sp = S_T + (size_t)(block_row >> 12) * 16384;
    short8 bf[4][4];   // [n][ks]
    #pragma unroll
    for (int n = 0; n < 4; n++) {
        const float* se = sp + (size_t)((nt0 + n) * 16 + r) * 128 + 8 * g;
        #pragma unroll
        for (int ks = 0; ks < 4; ks++) {
            float4 a = *(const float4*)(se + 32 * ks);
            float4 c = *(const float4*)(se + 32 * ks + 4);
            bf[n][ks] = pack_bf8(a, c);
        }
    }
    f32x4 acc[4];
    #pragma unroll
    for (int n = 0; n < 4; n++) acc[n] = (f32x4){0.f, 0.f, 0.f, 0.f};
    #pragma unroll
    for (int ks = 0; ks < 4; ks++)
        #pragma unroll
        for (int n = 0; n < 4; n++)
            acc[n] = __builtin_amdgcn_mfma_f32_16x16x32_bf16(
                af[ks], bf[n][ks], acc[n], 0, 0, 0);
    #pragma unroll
    for (int n = 0; n < 4; n++) {
        int col = (nt0 + n) * 16 + r;
        #pragma unroll
        for (int j = 0; j < 4; j++) {
            float v = 1.0f / (1.0f + __expf(-acc[n][j]));
            Cf[(size_t)(row0 + 4 * g + j) * DD + col] = v;
        }
    }
}

// ---------------------------------------------------------------- launch
extern "C" void kernel_launch(void* const* d_in, const int* in_sizes, int n_in,
                              void* d_out, int out_size, void* d_ws, size_t ws_size,
                              hipStream_t stream) {
    const float* x    = (const float*)d_in[0];
    const float* fx   = (const float*)d_in[1];
    const float* ln1g = (const float*)d_in[2];
    const float* ln1b = (const float*)d_in[3];
    const float* wq   = (const float*)d_in[4];
    const float* wk   = (const float*)d_in[5];
    const float* wv   = (const float*)d_in[6];
    const float* wo   = (const float*)d_in[7];
    const float* bo   = (const float*)d_in[8];
    const float* ln2g = (const float*)d_in[9];
    const float* ln2b = (const float*)d_in[10];
    const float* w1   = (const float*)d_in[11];
    const float* b1   = (const float*)d_in[12];
    const float* w2   = (const float*)d_in[13];
    const float* b2   = (const float*)d_in[14];

    float* out = (float*)d_out;
    float* xfinal = out;
    float* fxout  = out + (size_t)MM * DD;

    float* ws = (float*)d_ws;
    short* xbf    = (short*)ws;                        // 2M shorts (4MB)
    short* partSb = (short*)(ws + 1048576);            // 4M shorts (8MB)
    short* wfW    = (short*)(ws + 3145728);            // 5*16384 shorts = 40960 floats
    float* partC  = ws + 3145728 + 40960;              // 512*2048 f32 (4MB) — AFTER wfW (r7 bug: overlapped)
    float* pcs    = partC + 1048576;                   // 512*128 f32
    float* S_T    = pcs + 65536;                       // 4*16384 f32
    short* mtf    = (short*)(S_T + 65536);             // 4*16384 shorts

    wprep<<<40, 256, 0, stream>>>(wq, wk, wv, w1, w2, wfW);
    // LN1 + K,V + per-block ctx partials (ek/v never hit HBM; no atomics)
    lnctx<<<512, 256, 0, stream>>>(x, ln1g, ln1b, wfW + 16384, partC, pcs);
    build_mt_k<<<32, 256, 0, stream>>>(partC, pcs, wo, mtf);
    // LN1 + q + softmax + q@Mt + residual + LN2 + MLP + residual
    fused_mid<<<512, 256, 0, stream>>>(x, ln1g, ln1b, wfW, mtf, bo, ln2g, ln2b,
                                       wfW + 3 * 16384, b1, wfW + 4 * 16384, b2,
                                       xfinal, xbf);
    sbuild_p<<<256, 512, 0, stream>>>(xbf, fx, partSb);
    sreduce2<<<512, 256, 0, stream>>>(partSb, S_T);
    gemm_sig<<<512, 256, 0, stream>>>(xbf, S_T, fxout);
}

// Round 9
// 73.061 us; speedup vs baseline: 1.1548x; 1.1548x over previous
//
#include <hip/hip_runtime.h>
#include <math.h>

#define BB 4
#define NN 4096
#define DD 128
#define MM (BB*NN)   // 16384

typedef __attribute__((ext_vector_type(8))) short short8;
typedef __attribute__((ext_vector_type(4))) float f32x4;

__device__ inline short f2bf(float f) {
    unsigned u = __float_as_uint(f);
    u = (u + 0x7FFFu + ((u >> 16) & 1u)) >> 16;
    return (short)u;
}
__device__ inline float bf2f(short s) {
    return __uint_as_float(((unsigned)(unsigned short)s) << 16);
}
__device__ inline short8 pack_bf8(float4 a, float4 b) {
    short8 o;
    o[0] = f2bf(a.x); o[1] = f2bf(a.y); o[2] = f2bf(a.z); o[3] = f2bf(a.w);
    o[4] = f2bf(b.x); o[5] = f2bf(b.y); o[6] = f2bf(b.z); o[7] = f2bf(b.w);
    return o;
}
// swizzled LDS byte offset for a [32][128] bf16 tile (2-way max on b128 reads)
__device__ inline int swzoff(int row, int col) {
    return ((row * 128 + col) * 2) ^ ((row & 7) << 4);
}

// ---------------------------------------------------------------- weight preconvert to bf16 frag layout
// frag slot j = nt*256 + ks*64 + l ; elem i (0..7) = W[nt*16 + (l&15)][32*ks + 8*(l>>4) + i]
__global__ __launch_bounds__(256) void wprep(const float* __restrict__ w0, const float* __restrict__ w1,
                                             const float* __restrict__ w2, const float* __restrict__ w3,
                                             const float* __restrict__ w4, short* __restrict__ wf) {
    int m = blockIdx.x >> 3;
    int j = (blockIdx.x & 7) * 256 + threadIdx.x;
    const float* W = (m == 0) ? w0 : (m == 1) ? w1 : (m == 2) ? w2 : (m == 3) ? w3 : w4;
    int nt = j >> 8, ks = (j >> 6) & 3, l = j & 63, r = l & 15, g = l >> 4;
    const float* src = W + (size_t)(nt * 16 + r) * DD + 32 * ks + 8 * g;
    float4 a = *(const float4*)src;
    float4 b = *(const float4*)(src + 4);
    ((short8*)(wf + (size_t)m * 16384))[j] = pack_bf8(a, b);
}

// ---------------------------------------------------------------- LN1 + K,V GEMMs + ctx partial (atomic-free)
__global__ __launch_bounds__(256) void lnctx(const float* __restrict__ x,
                                             const float* __restrict__ lng,
                                             const float* __restrict__ lnb,
                                             const short* __restrict__ wf,   // wk frags, wv at +16384
                                             float* __restrict__ partC,
                                             float* __restrict__ pcs) {
    __shared__ float ekL[32][132];
    __shared__ float vL[32][132];
    int t = threadIdx.x;
    int block_row = blockIdx.x * 32;
    int w = t >> 6, l = t & 63, r = l & 15, g = l >> 4;
    int rh = w >> 1, nt0 = (w & 1) << 2;
    int row0 = block_row + rh * 16;

    const float* ap = x + (size_t)(row0 + r) * DD + 8 * g;
    float4 av0[4], av1[4];
    #pragma unroll
    for (int ks = 0; ks < 4; ks++) {
        av0[ks] = *(const float4*)(ap + 32 * ks);
        av1[ks] = *(const float4*)(ap + 32 * ks + 4);
    }
    float s = 0.f, ss = 0.f;
    #pragma unroll
    for (int ks = 0; ks < 4; ks++) {
        float4 a = av0[ks], b = av1[ks];
        s  += a.x + a.y + a.z + a.w + b.x + b.y + b.z + b.w;
        ss += a.x*a.x + a.y*a.y + a.z*a.z + a.w*a.w + b.x*b.x + b.y*b.y + b.z*b.z + b.w*b.w;
    }
    s  += __shfl_xor(s, 16);  s  += __shfl_xor(s, 32);
    ss += __shfl_xor(ss, 16); ss += __shfl_xor(ss, 32);
    float mu = s * (1.0f / DD);
    float var = ss * (1.0f / DD) - mu * mu;
    float rs = rsqrtf(var + 1e-6f);

    short8 af[4];
    #pragma unroll
    for (int ks = 0; ks < 4; ks++) {
        float4 g0 = *(const float4*)(lng + 32 * ks + 8 * g);
        float4 g1 = *(const float4*)(lng + 32 * ks + 8 * g + 4);
        float4 b0 = *(const float4*)(lnb + 32 * ks + 8 * g);
        float4 b1 = *(const float4*)(lnb + 32 * ks + 8 * g + 4);
        float4 n0, n1;
        n0.x = (av0[ks].x - mu) * rs * g0.x + b0.x;
        n0.y = (av0[ks].y - mu) * rs * g0.y + b0.y;
        n0.z = (av0[ks].z - mu) * rs * g0.z + b0.z;
        n0.w = (av0[ks].w - mu) * rs * g0.w + b0.w;
        n1.x = (av1[ks].x - mu) * rs * g1.x + b1.x;
        n1.y = (av1[ks].y - mu) * rs * g1.y + b1.y;
        n1.z = (av1[ks].z - mu) * rs * g1.z + b1.z;
        n1.w = (av1[ks].w - mu) * rs * g1.w + b1.w;
        af[ks] = pack_bf8(n0, n1);
    }

    f32x4 acc[2][4];
    #pragma unroll
    for (int m = 0; m < 2; m++)
        #pragma unroll
        for (int n = 0; n < 4; n++) acc[m][n] = (f32x4){0.f, 0.f, 0.f, 0.f};
    const short8* wp8 = (const short8*)wf;
    #pragma unroll
    for (int ks = 0; ks < 4; ks++)
        #pragma unroll
        for (int m = 0; m < 2; m++)
            #pragma unroll
            for (int n = 0; n < 4; n++)
                acc[m][n] = __builtin_amdgcn_mfma_f32_16x16x32_bf16(
                    af[ks], wp8[(size_t)m * 2048 + ((nt0 + n) * 4 + ks) * 64 + l], acc[m][n], 0, 0, 0);

    #pragma unroll
    for (int n = 0; n < 4; n++) {
        int col = (nt0 + n) * 16 + r;
        #pragma unroll
        for (int j = 0; j < 4; j++) {
            int rowL = rh * 16 + 4 * g + j;
            ekL[rowL][col] = __expf(acc[0][n][j]);
            vL[rowL][col]  = acc[1][n][j];
        }
    }
    __syncthreads();

    int h = t >> 5, sub = t & 31, d = sub >> 1, e0 = (sub & 1) * 8;
    float cs = 0.f;
    float sc[8] = {0.f, 0.f, 0.f, 0.f, 0.f, 0.f, 0.f, 0.f};
    #pragma unroll 8
    for (int row = 0; row < 32; row++) {
        float ekv = ekL[row][h * 16 + d];
        float4 v0 = *(const float4*)&vL[row][h * 16 + e0];
        float4 v1 = *(const float4*)&vL[row][h * 16 + e0 + 4];
        sc[0] += ekv * v0.x; sc[1] += ekv * v0.y; sc[2] += ekv * v0.z; sc[3] += ekv * v0.w;
        sc[4] += ekv * v1.x; sc[5] += ekv * v1.y; sc[6] += ekv * v1.z; sc[7] += ekv * v1.w;
        cs += ekv;
    }
    float* cb = partC + (size_t)blockIdx.x * 2048 + h * 256 + d * 16 + e0;
    *(float4*)cb       = (float4){sc[0], sc[1], sc[2], sc[3]};
    *(float4*)(cb + 4) = (float4){sc[4], sc[5], sc[6], sc[7]};
    if ((sub & 1) == 0) pcs[(size_t)blockIdx.x * 128 + h * 16 + d] = cs;
}

// ---------------------------------------------------------------- reduce ctx partials (coalesced tree)
// grid 64: b = k>>4, slots s0..s0+127 ; 128 chunks per b
__global__ __launch_bounds__(256) void ctxred(const float* __restrict__ part,
                                              float* __restrict__ ctxacc) {
    int k = blockIdx.x;
    int b = k >> 4, s0 = (k & 15) * 128;
    int t = threadIdx.x;
    int slot = s0 + (t & 127), half = t >> 7;
    float s = 0.f;
    #pragma unroll 8
    for (int c = half * 64; c < half * 64 + 64; c++)
        s += part[(size_t)((b << 7) + c) * 2048 + slot];
    __shared__ float red[128];
    if (half) red[t & 127] = s;
    __syncthreads();
    if (!half) ctxacc[(size_t)b * 2048 + slot] = s + red[t & 127];
}

// ---------------------------------------------------------------- ctx -> Mt frag (bf16); cs reduced in-kernel
__global__ __launch_bounds__(256) void build_mt_k(const float* __restrict__ ctxacc,
                                                  const float* __restrict__ pcs,
                                                  const float* __restrict__ wo,
                                                  short* __restrict__ mtfrag) {
    int b = blockIdx.x >> 3, nt = blockIdx.x & 7;
    int t = threadIdx.x;
    __shared__ float ctxL[2048];
    __shared__ float csL[128];
    __shared__ float woL[2048];
    #pragma unroll
    for (int i = 0; i < 8; i++) {
        int idx = i * 256 + t;
        ctxL[idx] = ctxacc[(size_t)b * 2048 + idx];
        woL[idx]  = wo[(size_t)(nt * 16) * DD + idx];
    }
    if (t < 128) {
        float s = 0.f;
        #pragma unroll 8
        for (int c = 0; c < 128; c++) s += pcs[(size_t)(b * 128 + c) * 128 + t];
        csL[t] = s;
    }
    __syncthreads();
    int ks = (t >> 6) & 3, l = t & 63, r = l & 15, g = l >> 4;
    short8 o;
    #pragma unroll
    for (int i2 = 0; i2 < 8; i2++) {
        int k = 32 * ks + 8 * g + i2;
        float inv = 1.0f / csL[k];
        const float* wrow = woL + r * DD + (k >> 4) * 16;
        float s = 0.f;
        #pragma unroll
        for (int eo = 0; eo < 16; eo++) s += ctxL[k * 16 + eo] * wrow[eo];
        o[i2] = f2bf(s * inv);
    }
    ((short8*)(mtfrag + (size_t)b * 16384))[nt * 256 + t] = o;
}

// ---------------------------------------------------------------- fused mid:
// LN1 -> q (MFMA + feature softmax) -> xmid = q@Mt + bo + x -> LN2 -> gelu GEMM -> final GEMM
__global__ __launch_bounds__(256) void fused_mid(const float* __restrict__ x,
                                                 const float* __restrict__ ln1g,
                                                 const float* __restrict__ ln1b,
                                                 const short* __restrict__ wqf,
                                                 const short* __restrict__ mtf,
                                                 const float* __restrict__ bo,
                                                 const float* __restrict__ ln2g,
                                                 const float* __restrict__ ln2b,
                                                 const short* __restrict__ w1f,
                                                 const float* __restrict__ b1,
                                                 const short* __restrict__ w2f,
                                                 const float* __restrict__ b2,
                                                 float* __restrict__ xfinal,
                                                 short* __restrict__ xbf) {
    __shared__ __align__(16) char ex[32 * 128 * 2];   // bf16 swizzled exchange (q, y, h1)
    __shared__ float ex2f[32][132];                   // f32 x tile for residual
    __shared__ float redS[4][16], redSS[4][16];
    int t = threadIdx.x;
    int block_row = blockIdx.x * 32;
    int w = t >> 6, l = t & 63, r = l & 15, g = l >> 4;
    int rh = w >> 1, nt0 = (w & 1) << 2;
    int row0 = block_row + rh * 16;
    int rrow = rh * 16 + r;

    const float* ap = x + (size_t)(row0 + r) * DD + 8 * g;
    float4 av0[4], av1[4];
    #pragma unroll
    for (int ks = 0; ks < 4; ks++) {
        av0[ks] = *(const float4*)(ap + 32 * ks);
        av1[ks] = *(const float4*)(ap + 32 * ks + 4);
    }
    if ((w & 1) == 0) {
        #pragma unroll
        for (int ks = 0; ks < 4; ks++) {
            *(float4*)&ex2f[rrow][32 * ks + 8 * g]     = av0[ks];
            *(float4*)&ex2f[rrow][32 * ks + 8 * g + 4] = av1[ks];
        }
    }
    float s = 0.f, ss = 0.f;
    #pragma unroll
    for (int ks = 0; ks < 4; ks++) {
        float4 a = av0[ks], b = av1[ks];
        s  += a.x + a.y + a.z + a.w + b.x + b.y + b.z + b.w;
        ss += a.x*a.x + a.y*a.y + a.z*a.z + a.w*a.w + b.x*b.x + b.y*b.y + b.z*b.z + b.w*b.w;
    }
    s  += __shfl_xor(s, 16);  s  += __shfl_xor(s, 32);
    ss += __shfl_xor(ss, 16); ss += __shfl_xor(ss, 32);
    float mu1 = s * (1.0f / DD);
    float var1 = ss * (1.0f / DD) - mu1 * mu1;
    float rs1 = rsqrtf(var1 + 1e-6f);
    short8 af[4];
    #pragma unroll
    for (int ks = 0; ks < 4; ks++) {
        float4 g0 = *(const float4*)(ln1g + 32 * ks + 8 * g);
        float4 g1 = *(const float4*)(ln1g + 32 * ks + 8 * g + 4);
        float4 b0 = *(const float4*)(ln1b + 32 * ks + 8 * g);
        float4 b1v = *(const float4*)(ln1b + 32 * ks + 8 * g + 4);
        float4 n0, n1;
        n0.x = (av0[ks].x - mu1) * rs1 * g0.x + b0.x;
        n0.y = (av0[ks].y - mu1) * rs1 * g0.y + b0.y;
        n0.z = (av0[ks].z - mu1) * rs1 * g0.z + b0.z;
        n0.w = (av0[ks].w - mu1) * rs1 * g0.w + b0.w;
        n1.x = (av1[ks].x - mu1) * rs1 * g1.x + b1v.x;
        n1.y = (av1[ks].y - mu1) * rs1 * g1.y + b1v.y;
        n1.z = (av1[ks].z - mu1) * rs1 * g1.z + b1v.z;
        n1.w = (av1[ks].w - mu1) * rs1 * g1.w + b1v.w;
        af[ks] = pack_bf8(n0, n1);
    }

    const short8* qp = (const short8*)wqf;
    f32x4 accq[4];
    #pragma unroll
    for (int n = 0; n < 4; n++) accq[n] = (f32x4){0.f, 0.f, 0.f, 0.f};
    #pragma unroll
    for (int ks = 0; ks < 4; ks++)
        #pragma unroll
        for (int n = 0; n < 4; n++)
            accq[n] = __builtin_amdgcn_mfma_f32_16x16x32_bf16(
                af[ks], qp[((nt0 + n) * 4 + ks) * 64 + l], accq[n], 0, 0, 0);
    #pragma unroll
    for (int n = 0; n < 4; n++) {
        int col = (nt0 + n) * 16 + r;
        #pragma unroll
        for (int j = 0; j < 4; j++) {
            float e = __expf(accq[n][j]);
            float sm = e;
            sm += __shfl_xor(sm, 1); sm += __shfl_xor(sm, 2);
            sm += __shfl_xor(sm, 4); sm += __shfl_xor(sm, 8);
            *(short*)(ex + swzoff(rh * 16 + 4 * g + j, col)) = f2bf(e / sm);
        }
    }
    __syncthreads();

    short8 qf[4];
    #pragma unroll
    for (int ks = 0; ks < 4; ks++)
        qf[ks] = *(const short8*)(ex + swzoff(rrow, 32 * ks + 8 * g));
    float xres[4][4];
    #pragma unroll
    for (int n = 0; n < 4; n++)
        #pragma unroll
        for (int j = 0; j < 4; j++)
            xres[n][j] = ex2f[rh * 16 + 4 * g + j][(nt0 + n) * 16 + r];

    const short8* mp = (const short8*)(mtf + (size_t)(block_row >> 12) * 16384);
    f32x4 acc[4];
    #pragma unroll
    for (int n = 0; n < 4; n++) acc[n] = (f32x4){0.f, 0.f, 0.f, 0.f};
    #pragma unroll
    for (int ks = 0; ks < 4; ks++)
        #pragma unroll
        for (int n = 0; n < 4; n++)
            acc[n] = __builtin_amdgcn_mfma_f32_16x16x32_bf16(
                qf[ks], mp[((nt0 + n) * 4 + ks) * 64 + l], acc[n], 0, 0, 0);

    float vv[4][4];
    #pragma unroll
    for (int n = 0; n < 4; n++) {
        int col = (nt0 + n) * 16 + r;
        float bv = bo[col];
        #pragma unroll
        for (int j = 0; j < 4; j++)
            vv[n][j] = acc[n][j] + bv + xres[n][j];
    }

    #pragma unroll
    for (int j = 0; j < 4; j++) {
        float s1  = vv[0][j] + vv[1][j] + vv[2][j] + vv[3][j];
        float s2 = vv[0][j]*vv[0][j] + vv[1][j]*vv[1][j] + vv[2][j]*vv[2][j] + vv[3][j]*vv[3][j];
        s1 += __shfl_xor(s1, 1); s1 += __shfl_xor(s1, 2); s1 += __shfl_xor(s1, 4); s1 += __shfl_xor(s1, 8);
        s2 += __shfl_xor(s2, 1); s2 += __shfl_xor(s2, 2); s2 += __shfl_xor(s2, 4); s2 += __shfl_xor(s2, 8);
        if (r == 0) { redS[w][4 * g + j] = s1; redSS[w][4 * g + j] = s2; }
    }
    __syncthreads();
    int base = w & 2;
    #pragma unroll
    for (int j = 0; j < 4; j++) {
        int rr = 4 * g + j;
        float S  = redS[base][rr]  + redS[base + 1][rr];
        float SS = redSS[base][rr] + redSS[base + 1][rr];
        float mu = S * (1.0f / DD);
        float var = SS * (1.0f / DD) - mu * mu;
        float rs = rsqrtf(var + 1e-6f);
        int rowL = rh * 16 + rr;
        #pragma unroll
        for (int n = 0; n < 4; n++) {
            int col = (nt0 + n) * 16 + r;
            float y = (vv[n][j] - mu) * rs * ln2g[col] + ln2b[col];
            *(short*)(ex + swzoff(rowL, col)) = f2bf(y);
        }
    }
    __syncthreads();
    short8 yf[4];
    #pragma unroll
    for (int ks = 0; ks < 4; ks++)
        yf[ks] = *(const short8*)(ex + swzoff(rrow, 32 * ks + 8 * g));
    __syncthreads();
    const short8* w1p = (const short8*)w1f;
    f32x4 acc2[4];
    #pragma unroll
    for (int n = 0; n < 4; n++) acc2[n] = (f32x4){0.f, 0.f, 0.f, 0.f};
    #pragma unroll
    for (int ks = 0; ks < 4; ks++)
        #pragma unroll
        for (int n = 0; n < 4; n++)
            acc2[n] = __builtin_amdgcn_mfma_f32_16x16x32_bf16(
                yf[ks], w1p[((nt0 + n) * 4 + ks) * 64 + l], acc2[n], 0, 0, 0);
    #pragma unroll
    for (int n = 0; n < 4; n++) {
        int col = (nt0 + n) * 16 + r;
        float bv = b1[col];
        #pragma unroll
        for (int j = 0; j < 4; j++) {
            float v = acc2[n][j] + bv;
            v = 0.5f * v * (1.0f + erff(v * 0.70710678118654752f));
            *(short*)(ex + swzoff(rh * 16 + 4 * g + j, col)) = f2bf(v);
        }
    }
    __syncthreads();
    short8 hf[4];
    #pragma unroll
    for (int ks = 0; ks < 4; ks++)
        hf[ks] = *(const short8*)(ex + swzoff(rrow, 32 * ks + 8 * g));
    const short8* w2p = (const short8*)w2f;
    f32x4 acc3[4];
    #pragma unroll
    for (int n = 0; n < 4; n++) acc3[n] = (f32x4){0.f, 0.f, 0.f, 0.f};
    #pragma unroll
    for (int ks = 0; ks < 4; ks++)
        #pragma unroll
        for (int n = 0; n < 4; n++)
            acc3[n] = __builtin_amdgcn_mfma_f32_16x16x32_bf16(
                hf[ks], w2p[((nt0 + n) * 4 + ks) * 64 + l], acc3[n], 0, 0, 0);
    #pragma unroll
    for (int n = 0; n < 4; n++) {
        int col = (nt0 + n) * 16 + r;
        float bv = b2[col];
        #pragma unroll
        for (int j = 0; j < 4; j++) {
            float v = acc3[n][j] + bv + vv[n][j];
            size_t row = (size_t)(row0 + 4 * g + j);
            xfinal[row * DD + col] = v;
            xbf[row * DD + col] = f2bf(v);
        }
    }
}

// ---------------------------------------------------------------- S partials (512 threads, 8 waves/CU)
// part[blk][e*128 + d] = sum_{64 rows} x[row,d] * fx[row,e]
__global__ __launch_bounds__(512) void sbuild_p(const short* __restrict__ xf,
                                                const float* __restrict__ fx,
                                                short* __restrict__ part) {
    int b = blockIdx.x >> 6, chunk = blockIdx.x & 63;
    int t = threadIdx.x;
    __shared__ float xs[64 * 128], fs[64 * 128];
    const short* xb = xf + ((size_t)b * NN + chunk * 64) * DD;
    const float* fb = fx + ((size_t)b * NN + chunk * 64) * DD;
    const short8* xg = (const short8*)xb;
    float4* xs4 = (float4*)xs; float4* fs4 = (float4*)fs;
    const float4* fg = (const float4*)fb;
    #pragma unroll
    for (int i = 0; i < 2; i++) {
        int j = i * 512 + t;             // 1024 short8
        short8 s8 = xg[j];
        float4 a = {bf2f(s8[0]), bf2f(s8[1]), bf2f(s8[2]), bf2f(s8[3])};
        float4 c = {bf2f(s8[4]), bf2f(s8[5]), bf2f(s8[6]), bf2f(s8[7])};
        xs4[2 * j] = a; xs4[2 * j + 1] = c;
    }
    #pragma unroll
    for (int i = 0; i < 4; i++) {
        int j = i * 512 + t;             // 2048 float4
        fs4[j] = fg[j];
    }
    __syncthreads();
    int td = t & 15, te = t >> 4;        // d0 = td*8 (8 d), e0 = te*4 (4 e)
    float acc[8][4];
    #pragma unroll
    for (int a = 0; a < 8; a++)
        #pragma unroll
        for (int c = 0; c < 4; c++) acc[a][c] = 0.f;
    for (int r = 0; r < 64; r++) {
        float4 x0 = xs4[r * 32 + td * 2], x1 = xs4[r * 32 + td * 2 + 1];
        float4 f0 = fs4[r * 32 + te];
        float xv[8] = {x0.x, x0.y, x0.z, x0.w, x1.x, x1.y, x1.z, x1.w};
        float fv[4] = {f0.x, f0.y, f0.z, f0.w};
        #pragma unroll
        for (int a = 0; a < 8; a++)
            #pragma unroll
            for (int c = 0; c < 4; c++) acc[a][c] = fmaf(xv[a], fv[c], acc[a][c]);
    }
    short* pb = part + (size_t)blockIdx.x * 16384;
    #pragma unroll
    for (int ci = 0; ci < 4; ci++) {
        short8 o;
        #pragma unroll
        for (int a = 0; a < 8; a++) o[a] = f2bf(acc[a][ci]);
        *(short8*)(pb + (size_t)(te * 4 + ci) * 128 + td * 8) = o;
    }
}

// ---------------------------------------------------------------- reduce S partials -> plain S_T[b][e][d] f32
// grid 512 = (b, e); vectorized short8 loads, wave shfl reduce, LDS combine
__global__ __launch_bounds__(256) void sreduce2(const short* __restrict__ part,
                                                float* __restrict__ S_T) {
    int b = blockIdx.x >> 7, e = blockIdx.x & 127;
    int t = threadIdx.x;
    int d8 = (t & 15) * 8;               // 16 d-groups of 8
    int ch0 = t >> 4;                    // 16 base chunks
    float s[8] = {0.f, 0.f, 0.f, 0.f, 0.f, 0.f, 0.f, 0.f};
    #pragma unroll
    for (int cc = 0; cc < 4; cc++) {
        int ch = ch0 + cc * 16;
        short8 u = *(const short8*)(part + (size_t)(b * 64 + ch) * 16384 + e * 128 + d8);
        #pragma unroll
        for (int i = 0; i < 8; i++) s[i] += bf2f(u[i]);
    }
    // combine lanes differing in t-bits 4,5 (same d8, different ch0) within the wave
    #pragma unroll
    for (int i = 0; i < 8; i++) {
        s[i] += __shfl_xor(s[i], 16);
        s[i] += __shfl_xor(s[i], 32);
    }
    __shared__ float red[4][128];
    int w = t >> 6;
    if ((t & 63) < 16) {
        #pragma unroll
        for (int i = 0; i < 8; i++) red[w][d8 + i] = s[i];
    }
    __syncthreads();
    if (t < 128)
        S_T[((size_t)b * 128 + e) * 128 + t] = red[0][t] + red[1][t] + red[2][t] + red[3][t];
}

// ---------------------------------------------------------------- final sigmoid GEMM (B-frags from plain S_T)
__global__ __launch_bounds__(256) void gemm_sig(const short* __restrict__ A,
                                                const float* __restrict__ S_T,
                                                float* __restrict__ Cf) {
    int t = threadIdx.x;
    int block_row = blockIdx.x * 32;
    int w = t >> 6, l = t & 63, r = l & 15, g = l >> 4;
    int row0 = block_row + ((w >> 1) << 4);
    int nt0 = (w & 1) << 2;
    const short8* ap = (const short8*)(A + (size_t)(row0 + r) * DD + 8 * g);
    short8 af[4];
    #pragma unroll
    for (int ks = 0; ks < 4; ks++) af[ks] = ap[ks * 4];
    // build B-frags: elem i = S[k=32ks+8g+i][e=nt*16+r] = S_T[e*128 + k]
    const float* sp = S_T + (size_t)(block_row >> 12) * 16384;
    short8 bf[4][4];   // [n][ks]
    #pragma unroll
    for (int n = 0; n < 4; n++) {
        const float* se = sp + (size_t)((nt0 + n) * 16 + r) * 128 + 8 * g;
        #pragma unroll
        for (int ks = 0; ks < 4; ks++) {
            float4 a = *(const float4*)(se + 32 * ks);
            float4 c = *(const float4*)(se + 32 * ks + 4);
            bf[n][ks] = pack_bf8(a, c);
        }
    }
    f32x4 acc[4];
    #pragma unroll
    for (int n = 0; n < 4; n++) acc[n] = (f32x4){0.f, 0.f, 0.f, 0.f};
    #pragma unroll
    for (int ks = 0; ks < 4; ks++)
        #pragma unroll
        for (int n = 0; n < 4; n++)
            acc[n] = __builtin_amdgcn_mfma_f32_16x16x32_bf16(
                af[ks], bf[n][ks], acc[n], 0, 0, 0);
    #pragma unroll
    for (int n = 0; n < 4; n++) {
        int col = (nt0 + n) * 16 + r;
        #pragma unroll
        for (int j = 0; j < 4; j++) {
            float v = 1.0f / (1.0f + __expf(-acc[n][j]));
            Cf[(size_t)(row0 + 4 * g + j) * DD + col] = v;
        }
    }
}

// ---------------------------------------------------------------- launch
extern "C" void kernel_launch(void* const* d_in, const int* in_sizes, int n_in,
                              void* d_out, int out_size, void* d_ws, size_t ws_size,
                              hipStream_t stream) {
    const float* x    = (const float*)d_in[0];
    const float* fx   = (const float*)d_in[1];
    const float* ln1g = (const float*)d_in[2];
    const float* ln1b = (const float*)d_in[3];
    const float* wq   = (const float*)d_in[4];
    const float* wk   = (const float*)d_in[5];
    const float* wv   = (const float*)d_in[6];
    const float* wo   = (const float*)d_in[7];
    const float* bo   = (const float*)d_in[8];
    const float* ln2g = (const float*)d_in[9];
    const float* ln2b = (const float*)d_in[10];
    const float* w1   = (const float*)d_in[11];
    const float* b1   = (const float*)d_in[12];
    const float* w2   = (const float*)d_in[13];
    const float* b2   = (const float*)d_in[14];

    float* out = (float*)d_out;
    float* xfinal = out;
    float* fxout  = out + (size_t)MM * DD;

    float* ws = (float*)d_ws;
    short* xbf    = (short*)ws;                        // 2M shorts (4MB)
    short* partSb = (short*)(ws + 1048576);            // 4M shorts (8MB)
    short* wfW    = (short*)(ws + 3145728);            // 5*16384 shorts = 40960 floats
    float* partC  = ws + 3145728 + 40960;              // 512*2048 f32 (4MB)
    float* pcs    = partC + 1048576;                   // 512*128 f32
    float* ctxacc = pcs + 65536;                       // 4*2048 f32
    float* S_T    = ctxacc + 8192;                     // 4*16384 f32
    short* mtf    = (short*)(S_T + 65536);             // 4*16384 shorts

    wprep<<<40, 256, 0, stream>>>(wq, wk, wv, w1, w2, wfW);
    // LN1 + K,V + per-block ctx partials (ek/v never hit HBM; no atomics)
    lnctx<<<512, 256, 0, stream>>>(x, ln1g, ln1b, wfW + 16384, partC, pcs);
    ctxred<<<64, 256, 0, stream>>>(partC, ctxacc);
    build_mt_k<<<32, 256, 0, stream>>>(ctxacc, pcs, wo, mtf);
    // LN1 + q + softmax + q@Mt + residual + LN2 + MLP + residual
    fused_mid<<<512, 256, 0, stream>>>(x, ln1g, ln1b, wfW, mtf, bo, ln2g, ln2b,
                                       wfW + 3 * 16384, b1, wfW + 4 * 16384, b2,
                                       xfinal, xbf);
    sbuild_p<<<256, 512, 0, stream>>>(xbf, fx, partSb);
    sreduce2<<<512, 256, 0, stream>>>(partSb, S_T);
    gemm_sig<<<512, 256, 0, stream>>>(xbf, S_T, fxout);
}